// Round 10
// baseline (928.768 us; speedup 1.0000x reference)
//
#include <hip/hip_runtime.h>
#include <math.h>

#define PI_F 3.14159265358979323846f
// DIAGNOSTIC #3 on the R9 (best, 286.7us) structure. Per-kernel REP so each
// kernel surfaces above the ~80us harness fills; fill split from k_mid so
// K3-compute and fill are measured separately for the first time.
#define REP1 16   // K1: pred ~8/rep  -> ~128us
#define REP2 16   // K2: pred ~6/rep  -> ~96us
#define REP3 8    // K3 compute-only: pred 15-18/rep -> 120-145us
#define REPF 8    // fill: pred ~16/rep -> ~130us
#define REP4 8    // K4 v3: pred 16/rep (staging worked) vs 29/rep (didn't)

// ---------------- K1: forward z-DFT ----------------------------------------
__global__ __launch_bounds__(256) void k_dft_z(const float* __restrict__ x,
                                               float2* __restrict__ T1) {
    int bid = blockIdx.x;
    int ih = bid & 1, yg = (bid >> 1) & 7, xx = (bid >> 4) & 15, b = bid >> 8;
    __shared__ float  sx[8192];      // [y8][z64][i16] 32KB
    __shared__ float2 twt[1024];     // [z][kz16] 8KB
    #pragma unroll 1
    for (int rep = 0; rep < REP1; ++rep) {
        float4* sx4 = (float4*)sx;
        const float4* src4 = (const float4*)(x + (size_t)((b * 64 + xx) * 64 + yg * 8) * 2048) + ih * 4;
        #pragma unroll
        for (int t = threadIdx.x; t < 2048; t += 256) {
            int i4 = t & 3, z = (t >> 2) & 63, y = t >> 8;
            sx4[(y * 64 + z) * 4 + i4] = src4[(size_t)y * 512 + z * 8 + i4];
        }
        const float cn = -2.0f * PI_F / 64.0f;
        for (int t = threadIdx.x; t < 1024; t += 256) {
            int z = t >> 4, kz = t & 15;
            float a = cn * (float)((z * kz) & 63);
            twt[t] = make_float2(__cosf(a), __sinf(a));
        }
        __syncthreads();
        int ig = threadIdx.x & 3, kz2 = (threadIdx.x >> 2) & 7, y8 = threadIdx.x >> 5;
        float ar0[4], ai0[4], ar1[4], ai1[4];
        #pragma unroll
        for (int j = 0; j < 4; j++) { ar0[j] = ai0[j] = ar1[j] = ai1[j] = 0.f; }
        const float4* twv = (const float4*)twt;
        #pragma unroll 8
        for (int z = 0; z < 64; z++) {
            float4 va = sx4[(y8 * 64 + z) * 4 + ig];
            float4 tp = twv[z * 8 + kz2];
            float v[4] = {va.x, va.y, va.z, va.w};
            #pragma unroll
            for (int j = 0; j < 4; j++) {
                ar0[j] = fmaf(v[j], tp.x, ar0[j]);
                ai0[j] = fmaf(v[j], tp.y, ai0[j]);
                ar1[j] = fmaf(v[j], tp.z, ar1[j]);
                ai1[j] = fmaf(v[j], tp.w, ai1[j]);
            }
        }
        int y = yg * 8 + y8, kz0 = kz2 * 2, i0 = ih * 16 + ig * 4;
        float2* dst = T1 + (size_t)((b * 16 + xx) * 64 + y) * 512;
        float4* d0 = (float4*)(dst + kz0 * 32 + i0);
        d0[0] = make_float4(ar0[0], ai0[0], ar0[1], ai0[1]);
        d0[1] = make_float4(ar0[2], ai0[2], ar0[3], ai0[3]);
        float4* d1 = (float4*)(dst + (kz0 + 1) * 32 + i0);
        d1[0] = make_float4(ar1[0], ai1[0], ar1[1], ai1[1]);
        d1[1] = make_float4(ar1[2], ai1[2], ar1[3], ai1[3]);
        __syncthreads();
        asm volatile("" ::: "memory");
    }
}

// ---------------- K2: forward y-DFT ----------------------------------------
__global__ __launch_bounds__(256) void k_dft_y(const float2* __restrict__ T1,
                                               float2* __restrict__ XH) {
    int bid = blockIdx.x;
    int ih = bid & 1, kzg = (bid >> 1) & 3, xx = (bid >> 3) & 15, b = bid >> 7;
    __shared__ float4 sT4[2304];     // ~37KB
    __shared__ float2 twt[1024];     // 8KB
    #pragma unroll 1
    for (int rep = 0; rep < REP2; ++rep) {
        const float4* Tg4 = (const float4*)T1;
        size_t gbase = (size_t)(b * 16 + xx) * 64 * 256;
        #pragma unroll
        for (int t = threadIdx.x; t < 2048; t += 256) {
            int i4 = t & 7, kz4 = (t >> 3) & 3, y = t >> 5;
            sT4[kz4 * 576 + y * 9 + i4] =
                Tg4[gbase + (size_t)y * 256 + (kzg * 4 + kz4) * 16 + ih * 8 + i4];
        }
        const float cn = -2.0f * PI_F / 64.0f;
        for (int t = threadIdx.x; t < 1024; t += 256) {
            int y = t >> 4, ky = t & 15;
            float a = cn * (float)((y * ky) & 63);
            twt[t] = make_float2(__cosf(a), __sinf(a));
        }
        __syncthreads();
        int ig = threadIdx.x & 7, ky2 = (threadIdx.x >> 3) & 7, kz4 = threadIdx.x >> 6;
        float ar[2][2], ai[2][2];
        #pragma unroll
        for (int h = 0; h < 2; h++) { ar[h][0] = ar[h][1] = ai[h][0] = ai[h][1] = 0.f; }
        const float4* twv = (const float4*)twt;
        #pragma unroll 8
        for (int y = 0; y < 64; y++) {
            float4 a  = sT4[kz4 * 576 + y * 9 + ig];
            float4 tp = twv[y * 8 + ky2];
            float xr[2] = {a.x, a.z}, xi[2] = {a.y, a.w};
            #pragma unroll
            for (int j = 0; j < 2; j++) {
                ar[0][j] += xr[j] * tp.x - xi[j] * tp.y;
                ai[0][j] += xr[j] * tp.y + xi[j] * tp.x;
                ar[1][j] += xr[j] * tp.z - xi[j] * tp.w;
                ai[1][j] += xr[j] * tp.w + xi[j] * tp.z;
            }
        }
        int kz = kzg * 4 + kz4;
        #pragma unroll
        for (int h = 0; h < 2; h++) {
            int ky = ky2 * 2 + h;
            float2* dp = XH + (((size_t)(b * 16 + xx) * 16 + ky) * 16 + kz) * 32 + ih * 16 + ig * 2;
            *(float4*)dp = make_float4(ar[h][0], ai[h][0], ar[h][1], ai[h][1]);
        }
        __syncthreads();
        asm volatile("" ::: "memory");
    }
}

// ---------------- K3: fused i-DFT + w-mul + o-IDFT (compute only) ----------
// grid 256 = (x16, ky16); block 512.
__global__ __launch_bounds__(512) void k_mid(const float2* __restrict__ XH,
                                             const float* __restrict__ wr,
                                             const float* __restrict__ wi,
                                             float2* __restrict__ G) {
    int bid = blockIdx.x;
    int ky = bid & 15, xx = bid >> 4;
    __shared__ float2 sA[4 * 528];
    __shared__ float2 sB[4 * 576];
    __shared__ float2 twt[1024];
    #pragma unroll 1
    for (int rep = 0; rep < REP3; ++rep) {
        for (int t = threadIdx.x; t < 2048; t += 512) {
            int b = t >> 9, kz = (t >> 5) & 15, i = t & 31;
            sA[b * 528 + kz * 33 + i] =
                XH[(((size_t)(b * 16 + xx) * 16 + ky) * 16 + kz) * 32 + i];
        }
        const float cn32 = -2.0f * PI_F / 32.0f;
        for (int t = threadIdx.x; t < 1024; t += 512) {
            int m = t >> 5, k = t & 31;
            float a = cn32 * (float)((m * k) & 31);
            twt[t] = make_float2(__cosf(a), __sinf(a));
        }
        __syncthreads();
        const float4* twv = (const float4*)twt;
        // phase 1
        {
            int kz = threadIdx.x & 15, kig = (threadIdx.x >> 4) & 7, b = threadIdx.x >> 7;
            float xr[4], xi[4];
            #pragma unroll
            for (int j = 0; j < 4; j++) { xr[j] = xi[j] = 0.f; }
            #pragma unroll 8
            for (int i = 0; i < 32; i++) {
                float2 a   = sA[b * 528 + kz * 33 + i];
                float4 tp0 = twv[i * 16 + kig * 2];
                float4 tp1 = twv[i * 16 + kig * 2 + 1];
                xr[0] += a.x * tp0.x - a.y * tp0.y;  xi[0] += a.x * tp0.y + a.y * tp0.x;
                xr[1] += a.x * tp0.z - a.y * tp0.w;  xi[1] += a.x * tp0.w + a.y * tp0.z;
                xr[2] += a.x * tp1.x - a.y * tp1.y;  xi[2] += a.x * tp1.y + a.y * tp1.x;
                xr[3] += a.x * tp1.z - a.y * tp1.w;  xi[3] += a.x * tp1.w + a.y * tp1.z;
            }
            #pragma unroll
            for (int j = 0; j < 4; j++)
                sB[b * 576 + (kig * 4 + j) * 18 + kz] = make_float2(xr[j], xi[j]);
        }
        __syncthreads();
        // phase 2
        {
            int kzg = threadIdx.x & 3, o = (threadIdx.x >> 2) & 31, b = threadIdx.x >> 7;
            int wbase = xx * 256 + ky * 16 + kzg * 4;
            float Fr[4], Fi[4];
            #pragma unroll
            for (int q = 0; q < 4; q++) { Fr[q] = Fi[q] = 0.f; }
            const float4* sB4 = (const float4*)sB;
            #pragma unroll 4
            for (int ki = 0; ki < 32; ki++) {
                float4 a01 = sB4[b * 288 + ki * 9 + kzg * 2];
                float4 a23 = sB4[b * 288 + ki * 9 + kzg * 2 + 1];
                float4 w4r = *(const float4*)(wr + (size_t)(ki * 32 + o) * 4096 + wbase);
                float4 w4i = *(const float4*)(wi + (size_t)(ki * 32 + o) * 4096 + wbase);
                float xr[4]  = {a01.x, a01.z, a23.x, a23.z};
                float xi[4]  = {a01.y, a01.w, a23.y, a23.w};
                float wrv[4] = {w4r.x, w4r.y, w4r.z, w4r.w};
                float wiv[4] = {w4i.x, w4i.y, w4i.z, w4i.w};
                #pragma unroll
                for (int q = 0; q < 4; q++) {
                    Fr[q] += xr[q] * wrv[q] - xi[q] * wiv[q];
                    Fi[q] += xr[q] * wiv[q] + xi[q] * wrv[q];
                }
            }
            __syncthreads();
            #pragma unroll
            for (int q = 0; q < 4; q++) {
                int kz = kzg * 4 + q;
                sA[b * 528 + kz * 33 + o] = make_float2(Fr[q], Fi[q]);
            }
        }
        __syncthreads();
        // phase 3
        {
            int kz = threadIdx.x & 15, cog = (threadIdx.x >> 4) & 7, b = threadIdx.x >> 7;
            float gr[4], gi[4];
            #pragma unroll
            for (int j = 0; j < 4; j++) { gr[j] = gi[j] = 0.f; }
            #pragma unroll 8
            for (int o = 0; o < 32; o++) {
                float2 f   = sA[b * 528 + kz * 33 + o];
                float4 tp0 = twv[o * 16 + cog * 2];
                float4 tp1 = twv[o * 16 + cog * 2 + 1];
                gr[0] += f.x * tp0.x + f.y * tp0.y;  gi[0] += f.y * tp0.x - f.x * tp0.y;
                gr[1] += f.x * tp0.z + f.y * tp0.w;  gi[1] += f.y * tp0.z - f.x * tp0.w;
                gr[2] += f.x * tp1.x + f.y * tp1.y;  gi[2] += f.y * tp1.x - f.x * tp1.y;
                gr[3] += f.x * tp1.z + f.y * tp1.w;  gi[3] += f.y * tp1.z - f.x * tp1.w;
            }
            float2* dp = G + (((size_t)(b * 16 + xx) * 16 + ky) * 16 + kz) * 32 + cog * 4;
            ((float4*)dp)[0] = make_float4(gr[0], gi[0], gr[1], gi[1]);
            ((float4*)dp)[1] = make_float4(gr[2], gi[2], gr[3], gi[3]);
        }
        __syncthreads();
        asm volatile("" ::: "memory");
    }
}

// ---------------- KF: zero-fill out[x>=16] (measured separately) -----------
// grid 1536; block 512; 64KB contiguous per block.
__global__ __launch_bounds__(512) void k_fill(float* __restrict__ out) {
    int f = blockIdx.x;
    int b = f / 384, rem = f - b * 384;
    float4* d4 = (float4*)(out + (size_t)(b * 64 + 16) * 131072) + (size_t)rem * 4096;
    #pragma unroll 1
    for (int rep = 0; rep < REPF; ++rep) {
        #pragma unroll
        for (int r = 0; r < 8; ++r)
            d4[r * 512 + threadIdx.x] = make_float4(0.f, 0.f, 0.f, 0.f);
        asm volatile("" ::: "memory");
    }
}

// ---------------- K4 v3: z-IDFT + y-IDFT + Re + scale (active x only) ------
__global__ __launch_bounds__(256) void k_idft_zy(const float2* __restrict__ G,
                                                 float* __restrict__ out) {
    int bid = blockIdx.x;
    int ch = bid & 1, zc = (bid >> 1) & 7, xx = (bid >> 4) & 15, b = bid >> 8;
    float* dstb = out + (size_t)(b * 64 + xx) * 131072;
    __shared__ float2 sGH[4096];     // sG 32KB, later aliased as sH (stride 18)
    __shared__ float2 twy[1024];
    __shared__ float2 twz[8 * 17];
    #pragma unroll 1
    for (int rep = 0; rep < REP4; ++rep) {
        const float cp = 2.0f * PI_F / 64.0f;
        for (int t = threadIdx.x; t < 1024; t += 256) {
            int ky = t >> 6, y = t & 63;
            float a = cp * (float)((ky * y) & 63);
            twy[t] = make_float2(__cosf(a), __sinf(a));
        }
        if (threadIdx.x < 128) {
            int dz = threadIdx.x >> 4, kz = threadIdx.x & 15;
            int z = zc * 8 + dz;
            float a = cp * (float)((kz * z) & 63);
            twz[dz * 17 + kz] = make_float2(__cosf(a), __sinf(a));
        }
        {
            const float2* Gb = G + (size_t)(b * 16 + xx) * 8192 + ch * 16;
            for (int t = threadIdx.x; t < 2048; t += 256) {
                int row = t >> 3, idx = t & 7;
                int ky = row >> 4, kz = row & 15;
                float4 v = *(const float4*)(Gb + (size_t)ky * 512 + kz * 32 + idx * 2);
                *(float4*)(&sGH[row * 16 + idx * 2]) = v;
            }
        }
        __syncthreads();
        int co = threadIdx.x & 15, dzp = (threadIdx.x >> 4) & 7, kyg = threadIdx.x >> 7;
        float hr[8], hi[8];
        {
            float tzc[16], tzs[16];
            #pragma unroll
            for (int kz = 0; kz < 16; ++kz) {
                float2 t = twz[dzp * 17 + kz];
                tzc[kz] = t.x; tzs[kz] = t.y;
            }
            #pragma unroll
            for (int t = 0; t < 8; ++t) {
                int ky = kyg * 8 + t;
                float r = 0.f, im = 0.f;
                #pragma unroll
                for (int kz = 0; kz < 16; ++kz) {
                    float2 g = sGH[(ky * 16 + kz) * 16 + co];
                    r  += g.x * tzc[kz] - g.y * tzs[kz];
                    im += g.x * tzs[kz] + g.y * tzc[kz];
                }
                hr[t] = r; hi[t] = im;
            }
        }
        __syncthreads();
        #pragma unroll
        for (int t = 0; t < 8; ++t) {
            int ky = kyg * 8 + t;
            sGH[(ky * 8 + dzp) * 18 + co] = make_float2(hr[t], hi[t]);
        }
        __syncthreads();
        {
            int cog = threadIdx.x & 1, dz = (threadIdx.x >> 1) & 7, yg = threadIdx.x >> 4;
            float acc[4][8];
            #pragma unroll
            for (int yl = 0; yl < 4; yl++)
                #pragma unroll
                for (int cl = 0; cl < 8; cl++) acc[yl][cl] = 0.f;
            const float4* twy4 = (const float4*)twy;
            const float4* sH4 = (const float4*)sGH;
            for (int ky = 0; ky < 16; ky++) {
                float4 t0 = twy4[ky * 32 + yg * 2 + 0];
                float4 t1 = twy4[ky * 32 + yg * 2 + 1];
                float4 h0 = sH4[(ky * 8 + dz) * 9 + cog * 4 + 0];
                float4 h1 = sH4[(ky * 8 + dz) * 9 + cog * 4 + 1];
                float4 h2 = sH4[(ky * 8 + dz) * 9 + cog * 4 + 2];
                float4 h3 = sH4[(ky * 8 + dz) * 9 + cog * 4 + 3];
                float tc[4] = {t0.x, t0.z, t1.x, t1.z};
                float ts[4] = {t0.y, t0.w, t1.y, t1.w};
                float hrv[8] = {h0.x, h0.z, h1.x, h1.z, h2.x, h2.z, h3.x, h3.z};
                float hiv[8] = {h0.y, h0.w, h1.y, h1.w, h2.y, h2.w, h3.y, h3.w};
                #pragma unroll
                for (int yl = 0; yl < 4; yl++)
                    #pragma unroll
                    for (int cl = 0; cl < 8; cl++)
                        acc[yl][cl] += tc[yl] * hrv[cl] - ts[yl] * hiv[cl];
            }
            const float sc = 1.0f / 131072.0f;
            #pragma unroll
            for (int yl = 0; yl < 4; yl++) {
                int y = yg * 4 + yl;
                float4* d4 = (float4*)(dstb + ((size_t)y * 64 + zc * 8 + dz) * 32 + ch * 16 + cog * 8);
                d4[0] = make_float4(acc[yl][0] * sc, acc[yl][1] * sc, acc[yl][2] * sc, acc[yl][3] * sc);
                d4[1] = make_float4(acc[yl][4] * sc, acc[yl][5] * sc, acc[yl][6] * sc, acc[yl][7] * sc);
            }
        }
        __syncthreads();
        asm volatile("" ::: "memory");
    }
}

extern "C" void kernel_launch(void* const* d_in, const int* in_sizes, int n_in,
                              void* d_out, int out_size, void* d_ws, size_t ws_size,
                              hipStream_t stream) {
    const float* x  = (const float*)d_in[0];
    const float* wr = (const float*)d_in[1];
    const float* wi = (const float*)d_in[2];
    float* out = (float*)d_out;
    char*  ws  = (char*)d_ws;
    float2* T1 = (float2*)ws;
    float2* XH = (float2*)(ws + (size_t)16777216);
    float2* Gb = (float2*)(ws + (size_t)16777216 + 4194304);

    k_dft_z  <<<1024, 256, 0, stream>>>(x, T1);
    k_dft_y  <<< 512, 256, 0, stream>>>(T1, XH);
    k_mid    <<< 256, 512, 0, stream>>>(XH, wr, wi, Gb);
    k_fill   <<<1536, 512, 0, stream>>>(out);
    k_idft_zy<<<1024, 256, 0, stream>>>(Gb, out);
}

// Round 11
// 296.801 us; speedup vs baseline: 3.1293x; 3.1293x over previous
//
#include <hip/hip_runtime.h>
#include <math.h>

#define PI_F 3.14159265358979323846f

// Shapes: B=4, X=Y=Z=64, CIN=COUT=32, modes 16.
// Round-11: K1/K2/K3+fill identical to R9 (best, 286.7us). K4 split:
//   K4a z-IDFT:  G(4.2MB) -> H(16.8MB, aliased over dead T1) ; 12KB LDS,
//                8 blk/CU, 512 FMA/thr, no phase chain. pred ~4-5us.
//   K4b y-IDFT:  H -> out (Re + 1/131072); grid 1024 (y-half split),
//                38.8KB LDS -> 4 blk/CU, 1024 FMA/thr. pred ~9-11us.
// R10 REP ledger: K1 8, K2 6, K3 16.6, fill 16 (write-roofline), K4 29
// (VALUBusy 44.6% => ~3.9k VALU inst/thr + 55% stalls) + ~212us floor.

// ---------------- K1: forward z-DFT ----------------------------------------
// grid 1024 = (b4, x16, yg8, ih2); block 256; tile 2kz x 4i per thread.
__global__ __launch_bounds__(256) void k_dft_z(const float* __restrict__ x,
                                               float2* __restrict__ T1) {
    int bid = blockIdx.x;
    int ih = bid & 1, yg = (bid >> 1) & 7, xx = (bid >> 4) & 15, b = bid >> 8;
    __shared__ float  sx[8192];      // [y8][z64][i16] 32KB
    __shared__ float2 twt[1024];     // [z][kz16] 8KB
    float4* sx4 = (float4*)sx;
    const float4* src4 = (const float4*)(x + (size_t)((b * 64 + xx) * 64 + yg * 8) * 2048) + ih * 4;
    #pragma unroll
    for (int t = threadIdx.x; t < 2048; t += 256) {
        int i4 = t & 3, z = (t >> 2) & 63, y = t >> 8;
        sx4[(y * 64 + z) * 4 + i4] = src4[(size_t)y * 512 + z * 8 + i4];
    }
    const float cn = -2.0f * PI_F / 64.0f;
    for (int t = threadIdx.x; t < 1024; t += 256) {
        int z = t >> 4, kz = t & 15;
        float a = cn * (float)((z * kz) & 63);
        twt[t] = make_float2(__cosf(a), __sinf(a));
    }
    __syncthreads();
    int ig = threadIdx.x & 3, kz2 = (threadIdx.x >> 2) & 7, y8 = threadIdx.x >> 5;
    float ar0[4], ai0[4], ar1[4], ai1[4];
    #pragma unroll
    for (int j = 0; j < 4; j++) { ar0[j] = ai0[j] = ar1[j] = ai1[j] = 0.f; }
    const float4* twv = (const float4*)twt;   // [z][8]: (c0,s0,c1,s1) per kz-pair
    #pragma unroll 8
    for (int z = 0; z < 64; z++) {
        float4 va = sx4[(y8 * 64 + z) * 4 + ig];
        float4 tp = twv[z * 8 + kz2];
        float v[4] = {va.x, va.y, va.z, va.w};
        #pragma unroll
        for (int j = 0; j < 4; j++) {
            ar0[j] = fmaf(v[j], tp.x, ar0[j]);
            ai0[j] = fmaf(v[j], tp.y, ai0[j]);
            ar1[j] = fmaf(v[j], tp.z, ar1[j]);
            ai1[j] = fmaf(v[j], tp.w, ai1[j]);
        }
    }
    int y = yg * 8 + y8, kz0 = kz2 * 2, i0 = ih * 16 + ig * 4;
    float2* dst = T1 + (size_t)((b * 16 + xx) * 64 + y) * 512;
    float4* d0 = (float4*)(dst + kz0 * 32 + i0);
    d0[0] = make_float4(ar0[0], ai0[0], ar0[1], ai0[1]);
    d0[1] = make_float4(ar0[2], ai0[2], ar0[3], ai0[3]);
    float4* d1 = (float4*)(dst + (kz0 + 1) * 32 + i0);
    d1[0] = make_float4(ar1[0], ai1[0], ar1[1], ai1[1]);
    d1[1] = make_float4(ar1[2], ai1[2], ar1[3], ai1[3]);
}

// ---------------- K2: forward y-DFT ----------------------------------------
// grid 512 = (b4, x16, kzg4, ih2); block 256; tile 2ky x 2i per thread.
__global__ __launch_bounds__(256) void k_dft_y(const float2* __restrict__ T1,
                                               float2* __restrict__ XH) {
    int bid = blockIdx.x;
    int ih = bid & 1, kzg = (bid >> 1) & 3, xx = (bid >> 3) & 15, b = bid >> 7;
    __shared__ float4 sT4[2304];     // [kz4][y(stride 9)][i4 8] ~37KB
    __shared__ float2 twt[1024];     // [y][ky16] 8KB
    const float4* Tg4 = (const float4*)T1;
    size_t gbase = (size_t)(b * 16 + xx) * 64 * 256;
    #pragma unroll
    for (int t = threadIdx.x; t < 2048; t += 256) {
        int i4 = t & 7, kz4 = (t >> 3) & 3, y = t >> 5;
        sT4[kz4 * 576 + y * 9 + i4] =
            Tg4[gbase + (size_t)y * 256 + (kzg * 4 + kz4) * 16 + ih * 8 + i4];
    }
    const float cn = -2.0f * PI_F / 64.0f;
    for (int t = threadIdx.x; t < 1024; t += 256) {
        int y = t >> 4, ky = t & 15;
        float a = cn * (float)((y * ky) & 63);
        twt[t] = make_float2(__cosf(a), __sinf(a));
    }
    __syncthreads();
    int ig = threadIdx.x & 7, ky2 = (threadIdx.x >> 3) & 7, kz4 = threadIdx.x >> 6;
    float ar[2][2], ai[2][2];
    #pragma unroll
    for (int h = 0; h < 2; h++) { ar[h][0] = ar[h][1] = ai[h][0] = ai[h][1] = 0.f; }
    const float4* twv = (const float4*)twt;
    #pragma unroll 8
    for (int y = 0; y < 64; y++) {
        float4 a  = sT4[kz4 * 576 + y * 9 + ig];   // (xr0,xi0,xr1,xi1)
        float4 tp = twv[y * 8 + ky2];              // (c0,s0,c1,s1)
        float xr[2] = {a.x, a.z}, xi[2] = {a.y, a.w};
        #pragma unroll
        for (int j = 0; j < 2; j++) {
            ar[0][j] += xr[j] * tp.x - xi[j] * tp.y;
            ai[0][j] += xr[j] * tp.y + xi[j] * tp.x;
            ar[1][j] += xr[j] * tp.z - xi[j] * tp.w;
            ai[1][j] += xr[j] * tp.w + xi[j] * tp.z;
        }
    }
    int kz = kzg * 4 + kz4;
    #pragma unroll
    for (int h = 0; h < 2; h++) {
        int ky = ky2 * 2 + h;
        float2* dp = XH + (((size_t)(b * 16 + xx) * 16 + ky) * 16 + kz) * 32 + ih * 16 + ig * 2;
        *(float4*)dp = make_float4(ar[h][0], ai[h][0], ar[h][1], ai[h][1]);
    }
}

// ---------------- K3: fused i-DFT + w-mul + o-IDFT + zero-fill -------------
// grid 1792 = 256 compute (x16, ky16) + 1536 fill; block 512.
__global__ __launch_bounds__(512) void k_mid(const float2* __restrict__ XH,
                                             const float* __restrict__ wr,
                                             const float* __restrict__ wi,
                                             float2* __restrict__ G,
                                             float* __restrict__ out) {
    int bid = blockIdx.x;
    if (bid >= 256) {
        // zero-fill out[b][16..63][*][*][*]: 1536 blocks x 64KB contiguous.
        int f = bid - 256;
        int b = f / 384, rem = f - b * 384;
        float4* d4 = (float4*)(out + (size_t)(b * 64 + 16) * 131072) + (size_t)rem * 4096;
        #pragma unroll
        for (int r = 0; r < 8; ++r)
            d4[r * 512 + threadIdx.x] = make_float4(0.f, 0.f, 0.f, 0.f);
        return;
    }
    int ky = bid & 15, xx = bid >> 4;
    __shared__ float2 sA[4 * 528];   // [b][kz(stride33)][i] ; reused as F[b][kz][o]
    __shared__ float2 sB[4 * 576];   // [b][ki(stride18)][kz]
    __shared__ float2 twt[1024];     // [m][k] = exp(-2pi i mk/32)
    for (int t = threadIdx.x; t < 2048; t += 512) {
        int b = t >> 9, kz = (t >> 5) & 15, i = t & 31;
        sA[b * 528 + kz * 33 + i] =
            XH[(((size_t)(b * 16 + xx) * 16 + ky) * 16 + kz) * 32 + i];
    }
    const float cn32 = -2.0f * PI_F / 32.0f;
    for (int t = threadIdx.x; t < 1024; t += 512) {
        int m = t >> 5, k = t & 31;
        float a = cn32 * (float)((m * k) & 31);
        twt[t] = make_float2(__cosf(a), __sinf(a));
    }
    __syncthreads();
    const float4* twv = (const float4*)twt;
    // phase 1: X2[b][ki][kz] = sum_i tw[ki,i] * XH[b][kz][i]  (4ki x 1kz per thread)
    {
        int kz = threadIdx.x & 15, kig = (threadIdx.x >> 4) & 7, b = threadIdx.x >> 7;
        float xr[4], xi[4];
        #pragma unroll
        for (int j = 0; j < 4; j++) { xr[j] = xi[j] = 0.f; }
        #pragma unroll 8
        for (int i = 0; i < 32; i++) {
            float2 a   = sA[b * 528 + kz * 33 + i];
            float4 tp0 = twv[i * 16 + kig * 2];       // ki = kig*4+0,1
            float4 tp1 = twv[i * 16 + kig * 2 + 1];   // ki = kig*4+2,3
            xr[0] += a.x * tp0.x - a.y * tp0.y;  xi[0] += a.x * tp0.y + a.y * tp0.x;
            xr[1] += a.x * tp0.z - a.y * tp0.w;  xi[1] += a.x * tp0.w + a.y * tp0.z;
            xr[2] += a.x * tp1.x - a.y * tp1.y;  xi[2] += a.x * tp1.y + a.y * tp1.x;
            xr[3] += a.x * tp1.z - a.y * tp1.w;  xi[3] += a.x * tp1.w + a.y * tp1.z;
        }
        #pragma unroll
        for (int j = 0; j < 4; j++)
            sB[b * 576 + (kig * 4 + j) * 18 + kz] = make_float2(xr[j], xi[j]);
    }
    __syncthreads();
    // phase 2: F[b][kz][o] = sum_ki X2[b][ki][kz] * w[ki,o]  (1o x 4kz per thread)
    {
        int kzg = threadIdx.x & 3, o = (threadIdx.x >> 2) & 31, b = threadIdx.x >> 7;
        int wbase = xx * 256 + ky * 16 + kzg * 4;
        float Fr[4], Fi[4];
        #pragma unroll
        for (int q = 0; q < 4; q++) { Fr[q] = Fi[q] = 0.f; }
        const float4* sB4 = (const float4*)sB;     // f4 stride 9 per ki
        #pragma unroll 4
        for (int ki = 0; ki < 32; ki++) {
            float4 a01 = sB4[b * 288 + ki * 9 + kzg * 2];
            float4 a23 = sB4[b * 288 + ki * 9 + kzg * 2 + 1];
            float4 w4r = *(const float4*)(wr + (size_t)(ki * 32 + o) * 4096 + wbase);
            float4 w4i = *(const float4*)(wi + (size_t)(ki * 32 + o) * 4096 + wbase);
            float xr[4]  = {a01.x, a01.z, a23.x, a23.z};
            float xi[4]  = {a01.y, a01.w, a23.y, a23.w};
            float wrv[4] = {w4r.x, w4r.y, w4r.z, w4r.w};
            float wiv[4] = {w4i.x, w4i.y, w4i.z, w4i.w};
            #pragma unroll
            for (int q = 0; q < 4; q++) {
                Fr[q] += xr[q] * wrv[q] - xi[q] * wiv[q];
                Fi[q] += xr[q] * wiv[q] + xi[q] * wrv[q];
            }
        }
        #pragma unroll
        for (int q = 0; q < 4; q++) {
            int kz = kzg * 4 + q;
            sA[b * 528 + kz * 33 + o] = make_float2(Fr[q], Fi[q]);
        }
    }
    __syncthreads();
    // phase 3: G[b][kz][co] = sum_o conj(tw[co,o]) * F[b][kz][o] (4co x 1kz per thread)
    {
        int kz = threadIdx.x & 15, cog = (threadIdx.x >> 4) & 7, b = threadIdx.x >> 7;
        float gr[4], gi[4];
        #pragma unroll
        for (int j = 0; j < 4; j++) { gr[j] = gi[j] = 0.f; }
        #pragma unroll 8
        for (int o = 0; o < 32; o++) {
            float2 f   = sA[b * 528 + kz * 33 + o];
            float4 tp0 = twv[o * 16 + cog * 2];       // co = cog*4+0,1
            float4 tp1 = twv[o * 16 + cog * 2 + 1];   // co = cog*4+2,3
            gr[0] += f.x * tp0.x + f.y * tp0.y;  gi[0] += f.y * tp0.x - f.x * tp0.y;
            gr[1] += f.x * tp0.z + f.y * tp0.w;  gi[1] += f.y * tp0.z - f.x * tp0.w;
            gr[2] += f.x * tp1.x + f.y * tp1.y;  gi[2] += f.y * tp1.x - f.x * tp1.y;
            gr[3] += f.x * tp1.z + f.y * tp1.w;  gi[3] += f.y * tp1.z - f.x * tp1.w;
        }
        float2* dp = G + (((size_t)(b * 16 + xx) * 16 + ky) * 16 + kz) * 32 + cog * 4;
        ((float4*)dp)[0] = make_float4(gr[0], gi[0], gr[1], gi[1]);
        ((float4*)dp)[1] = make_float4(gr[2], gi[2], gr[3], gi[3]);
    }
}

// ---------------- K4a: z-IDFT  G -> H --------------------------------------
// grid 1024 = (b4, x16, ky16); block 256; LDS 12KB -> 8 blk/CU.
// H[b,x,ky,z,co] = sum_kz exp(+2pi i kz z/64) * G[b,x,ky,kz,co]
__global__ __launch_bounds__(256) void k_idft_z(const float2* __restrict__ G,
                                                float2* __restrict__ H) {
    int bid = blockIdx.x;
    int ky = bid & 15, xx = (bid >> 4) & 15, b = bid >> 8;
    __shared__ float2 sG[512];       // [kz16][co32] 4KB
    __shared__ float2 twz[1024];     // [z64][kz16] 8KB
    size_t base = (((size_t)(b * 16 + xx) * 16 + ky)) * 512;
    for (int t = threadIdx.x; t < 512; t += 256)
        sG[t] = G[base + t];
    const float cp = 2.0f * PI_F / 64.0f;
    for (int t = threadIdx.x; t < 1024; t += 256) {
        int z = t >> 4, kz = t & 15;
        float a = cp * (float)((z * kz) & 63);
        twz[t] = make_float2(__cosf(a), __sinf(a));
    }
    __syncthreads();
    int co = threadIdx.x & 31, zq = threadIdx.x >> 5;    // zq 0..7
    float2* Hb = H + (((size_t)(b * 16 + xx) * 16 + ky)) * 2048;
    #pragma unroll
    for (int j = 0; j < 8; ++j) {
        int z = zq * 8 + j;
        float r = 0.f, im = 0.f;
        #pragma unroll
        for (int kz = 0; kz < 16; ++kz) {
            float2 t2 = twz[z * 16 + kz];
            float2 g  = sG[kz * 32 + co];
            r  += g.x * t2.x - g.y * t2.y;
            im += g.x * t2.y + g.y * t2.x;
        }
        Hb[z * 32 + co] = make_float2(r, im);
    }
}

// ---------------- K4b: y-IDFT + Re + scale  H -> out -----------------------
// grid 1024 = (b4, x16, zc8, yh2); block 256; LDS ~39KB -> 4 blk/CU.
// out[b,x,y,z,co] = sc * Re sum_ky exp(+2pi i ky y/64) * H[b,x,ky,z,co]
__global__ __launch_bounds__(256) void k_idft_y(const float2* __restrict__ H,
                                                float* __restrict__ out) {
    int bid = blockIdx.x;
    int yh = bid & 1, zc = (bid >> 1) & 7, xx = (bid >> 4) & 15, b = bid >> 8;
    float* dstb = out + (size_t)(b * 64 + xx) * 131072;   // [y][z][co]
    __shared__ float2 sH[128 * 34];  // row R=ky*8+dz, stride 34 f2 (17 f4), [co32]
    __shared__ float2 twy[512];      // [ky16][y32] (this y-half) 4KB
    // stage H slice: rows (ky,dz), 16 float4 per row, coalesced 256B chunks
    {
        const float2* Hb = H + ((size_t)(b * 16 + xx) * 16) * 2048 + (zc * 8) * 32;
        float4* sH4w = (float4*)sH;
        for (int t = threadIdx.x; t < 2048; t += 256) {
            int row = t >> 4, idx = t & 15;      // row = ky*8+dz
            int ky = row >> 3, dz = row & 7;
            float4 v = *(const float4*)(Hb + (size_t)ky * 2048 + dz * 32 + idx * 2);
            sH4w[row * 17 + idx] = v;
        }
    }
    const float cp = 2.0f * PI_F / 64.0f;
    for (int t = threadIdx.x; t < 512; t += 256) {
        int ky = t >> 5, yl = t & 31;
        int y = yh * 32 + yl;
        float a = cp * (float)((ky * y) & 63);
        twy[ky * 32 + yl] = make_float2(__cosf(a), __sinf(a));
    }
    __syncthreads();
    // thread = (coq4, dz8, yg8): 4 y x 8 co outputs, 1024 FMA
    {
        int coq = threadIdx.x & 3, dz = (threadIdx.x >> 2) & 7, yg = threadIdx.x >> 5;
        float acc[4][8];
        #pragma unroll
        for (int yl = 0; yl < 4; yl++)
            #pragma unroll
            for (int cl = 0; cl < 8; cl++) acc[yl][cl] = 0.f;
        const float4* twy4 = (const float4*)twy;   // [ky][y-pair 16]
        const float4* sH4 = (const float4*)sH;     // row stride 17 f4
        for (int ky = 0; ky < 16; ky++) {
            float4 t0 = twy4[ky * 16 + yg * 2 + 0];
            float4 t1 = twy4[ky * 16 + yg * 2 + 1];
            float4 h0 = sH4[(ky * 8 + dz) * 17 + coq * 4 + 0];
            float4 h1 = sH4[(ky * 8 + dz) * 17 + coq * 4 + 1];
            float4 h2 = sH4[(ky * 8 + dz) * 17 + coq * 4 + 2];
            float4 h3 = sH4[(ky * 8 + dz) * 17 + coq * 4 + 3];
            float tc[4] = {t0.x, t0.z, t1.x, t1.z};
            float ts[4] = {t0.y, t0.w, t1.y, t1.w};
            float hr[8] = {h0.x, h0.z, h1.x, h1.z, h2.x, h2.z, h3.x, h3.z};
            float hi[8] = {h0.y, h0.w, h1.y, h1.w, h2.y, h2.w, h3.y, h3.w};
            #pragma unroll
            for (int yl = 0; yl < 4; yl++)
                #pragma unroll
                for (int cl = 0; cl < 8; cl++)
                    acc[yl][cl] += tc[yl] * hr[cl] - ts[yl] * hi[cl];
        }
        const float sc = 1.0f / 131072.0f;
        #pragma unroll
        for (int yl = 0; yl < 4; yl++) {
            int y = yh * 32 + yg * 4 + yl;
            float4* d4 = (float4*)(dstb + ((size_t)y * 64 + zc * 8 + dz) * 32 + coq * 8);
            d4[0] = make_float4(acc[yl][0] * sc, acc[yl][1] * sc, acc[yl][2] * sc, acc[yl][3] * sc);
            d4[1] = make_float4(acc[yl][4] * sc, acc[yl][5] * sc, acc[yl][6] * sc, acc[yl][7] * sc);
        }
    }
}

extern "C" void kernel_launch(void* const* d_in, const int* in_sizes, int n_in,
                              void* d_out, int out_size, void* d_ws, size_t ws_size,
                              hipStream_t stream) {
    const float* x  = (const float*)d_in[0];
    const float* wr = (const float*)d_in[1];
    const float* wi = (const float*)d_in[2];
    float* out = (float*)d_out;
    char*  ws  = (char*)d_ws;
    // T1: 2,097,152 f2 (16.8 MB) @0  — dead after K2, reused as H by K4a/K4b.
    // XH: 524,288 f2 (4.2 MB) @16.8M; G: 524,288 f2 (4.2 MB) @21M.
    float2* T1 = (float2*)ws;
    float2* XH = (float2*)(ws + (size_t)16777216);
    float2* Gb = (float2*)(ws + (size_t)16777216 + 4194304);
    float2* Hb = T1;   // alias: H is exactly 2,097,152 f2

    k_dft_z <<<1024, 256, 0, stream>>>(x, T1);
    k_dft_y <<< 512, 256, 0, stream>>>(T1, XH);
    k_mid   <<<1792, 512, 0, stream>>>(XH, wr, wi, Gb, out);  // compute + fill
    k_idft_z<<<1024, 256, 0, stream>>>(Gb, Hb);
    k_idft_y<<<1024, 256, 0, stream>>>(Hb, out);
}